// Round 7
// baseline (1350.582 us; speedup 1.0000x reference)
//
#include <hip/hip_runtime.h>

#define NN 131072        // nodes
#define NE 2097152       // edges
#define NG 128           // graphs
#define KTOP 60
#define DTOT 385

// ======================= graph preprocessing =======================

__global__ void zero2_k(int* __restrict__ p) {
  p[blockIdx.x * 256 + threadIdx.x] = 0;
}

__global__ void count_k(const int* __restrict__ src, const int* __restrict__ dst,
                        int* __restrict__ cs, int* __restrict__ cd) {
  int e = blockIdx.x * 256 + threadIdx.x;
  atomicAdd(&cs[src[e]], 1);
  atomicAdd(&cd[dst[e]], 1);
}

__global__ void norm_k(const int* __restrict__ cs, const int* __restrict__ cd,
                       float* __restrict__ ns, float* __restrict__ nd) {
  int n = blockIdx.x * 256 + threadIdx.x;
  int a = cs[n]; a = a < 1 ? 1 : a;
  int b = cd[n]; b = b < 1 ? 1 : b;
  ns[n] = 1.0f / sqrtf((float)a);
  nd[n] = 1.0f / sqrtf((float)b);
}

// exclusive scan of NN ints: scan1 (per-1024 block) -> scan2 (128 partials) -> scan3 (add)
__global__ void scan1_k(const int* __restrict__ cnt, int* __restrict__ out,
                        int* __restrict__ partials) {
  __shared__ int ts[256];
  int t = threadIdx.x;
  int base = blockIdx.x * 1024 + t * 4;
  int v0 = cnt[base], v1 = cnt[base + 1], v2 = cnt[base + 2], v3 = cnt[base + 3];
  int s = v0 + v1 + v2 + v3;
  int x = s;
  ts[t] = x;
  __syncthreads();
  for (int off = 1; off < 256; off <<= 1) {
    int y = (t >= off) ? ts[t - off] : 0;
    __syncthreads();
    x += y; ts[t] = x;
    __syncthreads();
  }
  int excl = x - s;
  out[base]     = excl;
  out[base + 1] = excl + v0;
  out[base + 2] = excl + v0 + v1;
  out[base + 3] = excl + v0 + v1 + v2;
  if (t == 255) partials[blockIdx.x] = x;
}

__global__ void scan2_k(int* __restrict__ partials) {
  __shared__ int a[128];
  int t = threadIdx.x;
  int v = partials[t];
  int x = v; a[t] = x;
  __syncthreads();
  for (int off = 1; off < 128; off <<= 1) {
    int y = (t >= off) ? a[t - off] : 0;
    __syncthreads();
    x += y; a[t] = x;
    __syncthreads();
  }
  partials[t] = x - v;
}

__global__ void scan3_k(int* __restrict__ csr_off, const int* __restrict__ partials,
                        int* __restrict__ cursor) {
  int add = partials[blockIdx.x];
  int base = blockIdx.x * 1024 + threadIdx.x * 4;
  for (int i = 0; i < 4; ++i) {
    int v = csr_off[base + i] + add;
    csr_off[base + i] = v;
    cursor[base + i]  = v;
  }
  if (blockIdx.x == 0 && threadIdx.x == 0) csr_off[NN] = NE;
}

// csr_w[slot] = ew[e] * ns[src[e]]   (folds the source-side norm into the edge weight)
__global__ void fill_k(const int* __restrict__ src, const int* __restrict__ dst,
                       const float* __restrict__ ew, const float* __restrict__ ns,
                       int* __restrict__ cursor,
                       int* __restrict__ csrc, float* __restrict__ cw) {
  int e = blockIdx.x * 256 + threadIdx.x;
  int s = src[e];
  int d = dst[e];
  int slot = atomicAdd(&cursor[d], 1);
  csrc[slot] = s;
  cw[slot] = ew[e] * ns[s];
}

// ======================= node feature pipeline =======================
// GraphConv linearity: out = tanh( nd_n * (sum_j ew_j*ns_sj*x_sj) @ W + b )
// -> aggregate raw features first (aggX), then transform IN PLACE (gemm_inplace).

// layer 0 aggregate, embedding fused: t[n] = sum_j cw_j * zemb[z[csrc_j]]
__global__ void agg0_k(const int* __restrict__ z, const float* __restrict__ zemb,
                       const int* __restrict__ off, const int* __restrict__ csrc,
                       const float* __restrict__ cw, float* __restrict__ t) {
  int gid = blockIdx.x * 256 + threadIdx.x;
  int n = gid >> 5, q = gid & 31;
  int jb = off[n], je = off[n + 1];
  float4 s0 = {0, 0, 0, 0}, s1 = {0, 0, 0, 0};
  const float4* e4 = (const float4*)zemb;
  int j = jb;
  for (; j + 1 < je; j += 2) {
    int   a = csrc[j],  b = csrc[j + 1];
    float wa = cw[j],  wb = cw[j + 1];
    float4 ha = e4[(size_t)z[a] * 32 + q];
    float4 hb = e4[(size_t)z[b] * 32 + q];
    s0.x += ha.x * wa; s0.y += ha.y * wa; s0.z += ha.z * wa; s0.w += ha.w * wa;
    s1.x += hb.x * wb; s1.y += hb.y * wb; s1.z += hb.z * wb; s1.w += hb.w * wb;
  }
  if (j < je) {
    int a = csrc[j];
    float wa = cw[j];
    float4 ha = e4[(size_t)z[a] * 32 + q];
    s0.x += ha.x * wa; s0.y += ha.y * wa; s0.z += ha.z * wa; s0.w += ha.w * wa;
  }
  float4 o = {s0.x + s1.x, s0.y + s1.y, s0.z + s1.z, s0.w + s1.w};
  ((float4*)t)[(size_t)n * 32 + q] = o;
}

// layers 1,2 aggregate: t[n] = sum_j cw_j * x[csrc_j]
__global__ void aggx_k(const float* __restrict__ x, const int* __restrict__ off,
                       const int* __restrict__ csrc, const float* __restrict__ cw,
                       float* __restrict__ t) {
  int gid = blockIdx.x * 256 + threadIdx.x;
  int n = gid >> 5, q = gid & 31;
  int jb = off[n], je = off[n + 1];
  float4 s0 = {0, 0, 0, 0}, s1 = {0, 0, 0, 0};
  const float4* x4 = (const float4*)x;
  int j = jb;
  for (; j + 1 < je; j += 2) {
    int   a = csrc[j],  b = csrc[j + 1];
    float wa = cw[j],  wb = cw[j + 1];
    float4 ha = x4[(size_t)a * 32 + q];
    float4 hb = x4[(size_t)b * 32 + q];
    s0.x += ha.x * wa; s0.y += ha.y * wa; s0.z += ha.z * wa; s0.w += ha.w * wa;
    s1.x += hb.x * wb; s1.y += hb.y * wb; s1.z += hb.z * wb; s1.w += hb.w * wb;
  }
  if (j < je) {
    int a = csrc[j];
    float wa = cw[j];
    float4 ha = x4[(size_t)a * 32 + q];
    s0.x += ha.x * wa; s0.y += ha.y * wa; s0.z += ha.z * wa; s0.w += ha.w * wa;
  }
  float4 o = {s0.x + s1.x, s0.y + s1.y, s0.z + s1.z, s0.w + s1.w};
  ((float4*)t)[(size_t)n * 32 + q] = o;
}

__device__ __forceinline__ void fma4(float4& acc, float s, const float4 w) {
  acc.x += s * w.x; acc.y += s * w.y; acc.z += s * w.z; acc.w += s * w.w;
}

// IN PLACE: buf[n][:] <- tanh( nd[n] * (buf[n][:] @ W) + b ).  64 rows/block,
// rows staged in 32KB static LDS before any write (no dynamic LDS, no races).
// W (64KB) streams from global; it is L2-hot across all 2048 blocks.
__global__ void gemm_inplace_k(float* __restrict__ buf, const float* __restrict__ nd,
                               const float* __restrict__ W, const float* __restrict__ bias) {
  __shared__ float xt[64 * 128];   // 32 KB
  const int t = threadIdx.x;       // 256 threads
  const int rowBase = blockIdx.x * 64;
  float4* xt4 = (float4*)xt;
  const float4* g4 = (const float4*)(buf + (size_t)rowBase * 128);
  for (int i = t; i < 2048; i += 256) xt4[i] = g4[i];
  __syncthreads();
  const int w  = t >> 6;           // wave 0..3
  const int l  = t & 63;
  const int c4 = l & 31;           // output col group (cols 4*c4..4*c4+3)
  const int rh = l >> 5;           // row half within wave
  const int r0 = w * 16 + rh * 8;  // 8 rows: r0..r0+7
  float4 acc[8];
#pragma unroll
  for (int r = 0; r < 8; ++r) acc[r] = {0, 0, 0, 0};
  const float4* W4 = (const float4*)W;
  for (int k4 = 0; k4 < 32; ++k4) {
    float4 xv[8];
#pragma unroll
    for (int r = 0; r < 8; ++r) xv[r] = xt4[(r0 + r) * 32 + k4];
    const float4 w0 = W4[(k4 * 4 + 0) * 32 + c4];
    const float4 w1 = W4[(k4 * 4 + 1) * 32 + c4];
    const float4 w2 = W4[(k4 * 4 + 2) * 32 + c4];
    const float4 w3 = W4[(k4 * 4 + 3) * 32 + c4];
#pragma unroll
    for (int r = 0; r < 8; ++r) {
      fma4(acc[r], xv[r].x, w0);
      fma4(acc[r], xv[r].y, w1);
      fma4(acc[r], xv[r].z, w2);
      fma4(acc[r], xv[r].w, w3);
    }
  }
  const float4 bb = ((const float4*)bias)[c4];
#pragma unroll
  for (int r = 0; r < 8; ++r) {
    const int row = rowBase + r0 + r;
    const float s = nd[row];
    float4 o;
    o.x = tanhf(acc[r].x * s + bb.x);
    o.y = tanhf(acc[r].y * s + bb.y);
    o.z = tanhf(acc[r].z * s + bb.z);
    o.w = tanhf(acc[r].w * s + bb.w);
    ((float4*)(buf + (size_t)row * 128))[c4] = o;
  }
}

// layer 3 fused: xs3[n] = tanh( nd_n * dot(sum_j cw_j*xs2[csrc_j], W3) + b3 )
__global__ void agg3f_k(const float* __restrict__ x, const int* __restrict__ off,
                        const int* __restrict__ csrc, const float* __restrict__ cw,
                        const float* __restrict__ nd, const float* __restrict__ W3,
                        const float* __restrict__ b3, float* __restrict__ xs3) {
  int gid = blockIdx.x * 256 + threadIdx.x;
  int n = gid >> 5, q = gid & 31;
  int jb = off[n], je = off[n + 1];
  float4 s = {0, 0, 0, 0};
  const float4* x4 = (const float4*)x;
  for (int j = jb; j < je; ++j) {
    int a = csrc[j];
    float wa = cw[j];
    float4 h = x4[(size_t)a * 32 + q];
    s.x += h.x * wa; s.y += h.y * wa; s.z += h.z * wa; s.w += h.w * wa;
  }
  const float4 w4 = ((const float4*)W3)[q];
  float p = s.x * w4.x + s.y * w4.y + s.z * w4.z + s.w * w4.w;
  for (int o = 16; o; o >>= 1) p += __shfl_down(p, o);   // reduce each 32-lane half
  if (q == 0) xs3[n] = tanhf(p * nd[n] + b3[0]);
}

// ======================= sort-pool =======================

__global__ void nodemax_k(const float* __restrict__ xs0, const float* __restrict__ xs1,
                          const float* __restrict__ xs2, const float* __restrict__ xs3,
                          float* __restrict__ nmax) {
  int lane = threadIdx.x & 63, wv = threadIdx.x >> 6;
  int n = blockIdx.x * 4 + wv;
  const float* r0 = xs0 + (size_t)n * 128;
  const float* r1 = xs1 + (size_t)n * 128;
  const float* r2 = xs2 + (size_t)n * 128;
  float m = fmaxf(r0[lane], r0[lane + 64]);
  m = fmaxf(m, fmaxf(r1[lane], r1[lane + 64]));
  m = fmaxf(m, fmaxf(r2[lane], r2[lane + 64]));
  for (int o = 32; o; o >>= 1) m = fmaxf(m, __shfl_down(m, o));
  if (lane == 0) nmax[n] = fmaxf(m, xs3[n]);
}

// per-graph: sort 1024 (val,idx) pairs desc by val, asc by idx (jax.lax.top_k tie rule)
__global__ void topk_k(const float* __restrict__ nmax, int* __restrict__ sel) {
  __shared__ float v[1024];
  __shared__ int ix[1024];
  int g = blockIdx.x, t = threadIdx.x;  // 512 threads
  for (int i = t; i < 1024; i += 512) { v[i] = nmax[(size_t)g * 1024 + i]; ix[i] = i; }
  __syncthreads();
  for (int k = 2; k <= 1024; k <<= 1) {
    for (int j = k >> 1; j > 0; j >>= 1) {
      int i = ((t & ~(j - 1)) << 1) | (t & (j - 1));
      int pj = i | j;
      bool up = ((i & k) == 0);
      float va = v[i], vb = v[pj];
      int ia = ix[i], ib = ix[pj];
      bool b_bef_a = (vb > va) || (vb == va && ib < ia);
      bool a_bef_b = (va > vb) || (va == vb && ia < ib);
      bool sw = up ? b_bef_a : a_bef_b;
      if (sw) { v[i] = vb; v[pj] = va; ix[i] = ib; ix[pj] = ia; }
      __syncthreads();
    }
  }
  if (t < KTOP) sel[g * KTOP + t] = g * 1024 + ix[t];
}

// per selected node: ascending sort its 385 channel values (pad to 512 with +inf)
__global__ void sortpool_k(const int* __restrict__ sel, const float* __restrict__ xs0,
                           const float* __restrict__ xs1, const float* __restrict__ xs2,
                           const float* __restrict__ xs3, float* __restrict__ pooled) {
  __shared__ float sv[512];
  int blk = blockIdx.x, t = threadIdx.x;  // 256 threads
  int node = sel[blk];
  const float inf = __int_as_float(0x7f800000);
  for (int i = t; i < 512; i += 256) {
    float val;
    if (i < 128)      val = xs0[(size_t)node * 128 + i];
    else if (i < 256) val = xs1[(size_t)node * 128 + (i - 128)];
    else if (i < 384) val = xs2[(size_t)node * 128 + (i - 256)];
    else if (i == 384) val = xs3[node];
    else val = inf;
    sv[i] = val;
  }
  __syncthreads();
  for (int k = 2; k <= 512; k <<= 1) {
    for (int j = k >> 1; j > 0; j >>= 1) {
      int i = ((t & ~(j - 1)) << 1) | (t & (j - 1));
      int pj = i | j;
      bool up = ((i & k) == 0);
      float a = sv[i], b = sv[pj];
      if (up ? (a > b) : (a < b)) { sv[i] = b; sv[pj] = a; }
      __syncthreads();
    }
  }
  for (int i = t; i < DTOT; i += 256) pooled[(size_t)blk * DTOT + i] = sv[i];
}

// ======================= conv/MLP head (one block per graph) =======================

__global__ void head_k(const float* __restrict__ pooled,
                       const float* __restrict__ c1w, const float* __restrict__ c1b,
                       const float* __restrict__ c2w, const float* __restrict__ c2b,
                       const float* __restrict__ l1w, const float* __restrict__ l1b,
                       const float* __restrict__ l2w, const float* __restrict__ l2b,
                       float* __restrict__ out) {
  __shared__ float h1[16 * 60];
  __shared__ float h1p[16 * 30];
  __shared__ float h2f[832];
  __shared__ float h3[128];
  int g = blockIdx.x, t = threadIdx.x;  // 256 threads
  const float* pg = pooled + (size_t)g * KTOP * DTOT;
  for (int oi = t; oi < 960; oi += 256) {
    int c = oi & 15, kk = oi >> 4;
    const float* pr = pg + kk * DTOT;
    const float* wr = c1w + c * DTOT;
    float s = c1b[c];
    for (int d = 0; d < DTOT; ++d) s += pr[d] * wr[d];
    h1[c * 60 + kk] = fmaxf(s, 0.f);
  }
  __syncthreads();
  for (int i = t; i < 480; i += 256) {
    int c = i / 30, j = i % 30;
    h1p[c * 30 + j] = fmaxf(h1[c * 60 + 2 * j], h1[c * 60 + 2 * j + 1]);
  }
  __syncthreads();
  for (int i = t; i < 832; i += 256) {
    int oc = i / 26, x = i % 26;
    float s = c2b[oc];
    for (int ic = 0; ic < 16; ++ic)
#pragma unroll
      for (int w = 0; w < 5; ++w)
        s += h1p[ic * 30 + x + w] * c2w[oc * 80 + ic * 5 + w];
    h2f[i] = fmaxf(s, 0.f);
  }
  __syncthreads();
  if (t < 128) {
    float s = l1b[t];
    for (int d = 0; d < 832; ++d) s += h2f[d] * l1w[d * 128 + t];
    h3[t] = fmaxf(s, 0.f);
  }
  __syncthreads();
  if (t < 64) {
    float p = h3[t] * l2w[t] + h3[t + 64] * l2w[t + 64];
    for (int o = 32; o; o >>= 1) p += __shfl_down(p, o);
    if (t == 0) out[g] = p + l2b[0];
  }
}

// ======================= driver =======================

extern "C" void kernel_launch(void* const* d_in, const int* in_sizes, int n_in,
                              void* d_out, int out_size, void* d_ws, size_t ws_size,
                              hipStream_t stream) {
  const int* z = (const int*)d_in[0];
  const int* src = (const int*)d_in[1];
  const int* dst = (const int*)d_in[2];
  const float* ew = (const float*)d_in[3];
  const float* zemb = (const float*)d_in[4];
  const float* W0 = (const float*)d_in[5];  const float* b0 = (const float*)d_in[6];
  const float* W1 = (const float*)d_in[7];  const float* b1 = (const float*)d_in[8];
  const float* W2 = (const float*)d_in[9];  const float* b2 = (const float*)d_in[10];
  const float* W3 = (const float*)d_in[11]; const float* b3 = (const float*)d_in[12];
  const float* c1w = (const float*)d_in[13]; const float* c1b = (const float*)d_in[14];
  const float* c2w = (const float*)d_in[15]; const float* c2b = (const float*)d_in[16];
  const float* l1w = (const float*)d_in[17]; const float* l1b = (const float*)d_in[18];
  const float* l2w = (const float*)d_in[19]; const float* l2b = (const float*)d_in[20];
  float* out = (float*)d_out;

  // workspace layout (256B aligned); total ~234 MB (223 MiB)
  char* ws = (char*)d_ws;
  size_t off = 0;
  auto alloc = [&](size_t bytes) {
    void* p = ws + off;
    off += (bytes + 255) & ~(size_t)255;
    return p;
  };
  int*   cnt     = (int*)alloc((size_t)2 * NN * 4);   // cnt_s | cnt_d contiguous
  float* norm_s  = (float*)alloc((size_t)NN * 4);
  float* norm_d  = (float*)alloc((size_t)NN * 4);
  int*   csr_off = (int*)alloc((size_t)(NN + 1) * 4);
  int*   cursor  = (int*)alloc((size_t)NN * 4);
  int*   partials= (int*)alloc(1024);
  int*   csr_src = (int*)alloc((size_t)NE * 4);
  float* csr_w   = (float*)alloc((size_t)NE * 4);
  float* xs0     = (float*)alloc((size_t)NN * 128 * 4);
  float* xs1     = (float*)alloc((size_t)NN * 128 * 4);
  float* xs2     = (float*)alloc((size_t)NN * 128 * 4);
  float* xs3     = (float*)alloc((size_t)NN * 4);
  float* nmax    = (float*)alloc((size_t)NN * 4);
  int*   sel     = (int*)alloc((size_t)NG * KTOP * 4);
  float* pooled  = (float*)alloc((size_t)NG * KTOP * DTOT * 4);
  (void)in_sizes; (void)n_in; (void)out_size;
  if (ws_size < off) return;   // guard: never write OOB; fail diagnosably instead

  int* cnt_s = cnt;
  int* cnt_d = cnt + NN;

  // ---- CSR build + norms ----
  zero2_k<<<2 * NN / 256, 256, 0, stream>>>(cnt);
  count_k<<<NE / 256, 256, 0, stream>>>(src, dst, cnt_s, cnt_d);
  norm_k<<<NN / 256, 256, 0, stream>>>(cnt_s, cnt_d, norm_s, norm_d);
  scan1_k<<<128, 256, 0, stream>>>(cnt_d, csr_off, partials);
  scan2_k<<<1, 128, 0, stream>>>(partials);
  scan3_k<<<128, 256, 0, stream>>>(csr_off, partials, cursor);
  fill_k<<<NE / 256, 256, 0, stream>>>(src, dst, ew, norm_s, cursor, csr_src, csr_w);

  // ---- 3 GraphConv layers 128->128 (aggregate-first, in-place transform) ----
  agg0_k<<<NN * 32 / 256, 256, 0, stream>>>(z, zemb, csr_off, csr_src, csr_w, xs0);
  gemm_inplace_k<<<NN / 64, 256, 0, stream>>>(xs0, norm_d, W0, b0);
  aggx_k<<<NN * 32 / 256, 256, 0, stream>>>(xs0, csr_off, csr_src, csr_w, xs1);
  gemm_inplace_k<<<NN / 64, 256, 0, stream>>>(xs1, norm_d, W1, b1);
  aggx_k<<<NN * 32 / 256, 256, 0, stream>>>(xs1, csr_off, csr_src, csr_w, xs2);
  gemm_inplace_k<<<NN / 64, 256, 0, stream>>>(xs2, norm_d, W2, b2);

  // ---- layer 3: 128->1 fused ----
  agg3f_k<<<NN * 32 / 256, 256, 0, stream>>>(xs2, csr_off, csr_src, csr_w,
                                             norm_d, W3, b3, xs3);

  // ---- sort-pool ----
  nodemax_k<<<NN / 4, 256, 0, stream>>>(xs0, xs1, xs2, xs3, nmax);
  topk_k<<<NG, 512, 0, stream>>>(nmax, sel);
  sortpool_k<<<NG * KTOP, 256, 0, stream>>>(sel, xs0, xs1, xs2, xs3, pooled);

  // ---- head ----
  head_k<<<NG, 256, 0, stream>>>(pooled, c1w, c1b, c2w, c2b, l1w, l1b, l2w, l2b, out);
}

// Round 10
// 1184.412 us; speedup vs baseline: 1.1403x; 1.1403x over previous
//
#include <hip/hip_runtime.h>

#define NN 131072        // nodes
#define NE 2097152       // edges
#define NG 128           // graphs
#define KTOP 60
#define DTOT 385

// ======================= graph preprocessing =======================

__global__ void zero2_k(int* __restrict__ p) {
  p[blockIdx.x * 256 + threadIdx.x] = 0;
}

__global__ void count_k(const int* __restrict__ src, const int* __restrict__ dst,
                        int* __restrict__ cs, int* __restrict__ cd) {
  int e = blockIdx.x * 256 + threadIdx.x;
  atomicAdd(&cs[src[e]], 1);
  atomicAdd(&cd[dst[e]], 1);
}

__global__ void norm_k(const int* __restrict__ cs, const int* __restrict__ cd,
                       float* __restrict__ ns, float* __restrict__ nd) {
  int n = blockIdx.x * 256 + threadIdx.x;
  int a = cs[n]; a = a < 1 ? 1 : a;
  int b = cd[n]; b = b < 1 ? 1 : b;
  ns[n] = 1.0f / sqrtf((float)a);
  nd[n] = 1.0f / sqrtf((float)b);
}

// exclusive scan of NN ints
__global__ void scan1_k(const int* __restrict__ cnt, int* __restrict__ out,
                        int* __restrict__ partials) {
  __shared__ int ts[256];
  int t = threadIdx.x;
  int base = blockIdx.x * 1024 + t * 4;
  int v0 = cnt[base], v1 = cnt[base + 1], v2 = cnt[base + 2], v3 = cnt[base + 3];
  int s = v0 + v1 + v2 + v3;
  int x = s;
  ts[t] = x;
  __syncthreads();
  for (int off = 1; off < 256; off <<= 1) {
    int y = (t >= off) ? ts[t - off] : 0;
    __syncthreads();
    x += y; ts[t] = x;
    __syncthreads();
  }
  int excl = x - s;
  out[base]     = excl;
  out[base + 1] = excl + v0;
  out[base + 2] = excl + v0 + v1;
  out[base + 3] = excl + v0 + v1 + v2;
  if (t == 255) partials[blockIdx.x] = x;
}

__global__ void scan2_k(int* __restrict__ partials) {
  __shared__ int a[128];
  int t = threadIdx.x;
  int v = partials[t];
  int x = v; a[t] = x;
  __syncthreads();
  for (int off = 1; off < 128; off <<= 1) {
    int y = (t >= off) ? a[t - off] : 0;
    __syncthreads();
    x += y; a[t] = x;
    __syncthreads();
  }
  partials[t] = x - v;
}

__global__ void scan3_k(int* __restrict__ csr_off, const int* __restrict__ partials,
                        int* __restrict__ cursor) {
  int add = partials[blockIdx.x];
  int base = blockIdx.x * 1024 + threadIdx.x * 4;
  for (int i = 0; i < 4; ++i) {
    int v = csr_off[base + i] + add;
    csr_off[base + i] = v;
    cursor[base + i]  = v;
  }
  if (blockIdx.x == 0 && threadIdx.x == 0) csr_off[NN] = NE;
}

// csr[slot] = { src, ew*ns[src] }  (interleaved 8B, one random store per edge)
__global__ void fill_k(const int* __restrict__ src, const int* __restrict__ dst,
                       const float* __restrict__ ew, const float* __restrict__ ns,
                       int* __restrict__ cursor, int2* __restrict__ csr) {
  int e = blockIdx.x * 256 + threadIdx.x;
  int s = src[e];
  int d = dst[e];
  int slot = atomicAdd(&cursor[d], 1);
  csr[slot] = make_int2(s, __float_as_int(ew[e] * ns[s]));
}

// ======================= node feature pipeline =======================
// GraphConv linearity: out = tanh( nd_n * (sum_j ew_j*ns_sj*x_sj) @ W + b )

// One WAVE per node; the two 32-lane halves split the edge list by parity
// (no inter-node divergence); each half keeps 2 gathers in flight.
// layer 0: rows come from zemb[z[a]] (512 KB table, L2-resident)
__global__ void agg0_k(const int* __restrict__ z, const float* __restrict__ zemb,
                       const int* __restrict__ off, const int2* __restrict__ csr,
                       float* __restrict__ t) {
  int n = (blockIdx.x * 256 + threadIdx.x) >> 6;
  int lane = threadIdx.x & 63;
  int h = lane >> 5, q = lane & 31;
  int jb = off[n], je = off[n + 1];
  float4 s0 = {0, 0, 0, 0}, s1 = {0, 0, 0, 0};
  const float4* e4 = (const float4*)zemb;
  int j = jb + h;
  for (; j + 2 < je; j += 4) {
    int2 pa = csr[j], pb = csr[j + 2];
    float4 ha = e4[(size_t)z[pa.x] * 32 + q];
    float4 hb = e4[(size_t)z[pb.x] * 32 + q];
    float wa = __int_as_float(pa.y), wb = __int_as_float(pb.y);
    s0.x += ha.x * wa; s0.y += ha.y * wa; s0.z += ha.z * wa; s0.w += ha.w * wa;
    s1.x += hb.x * wb; s1.y += hb.y * wb; s1.z += hb.z * wb; s1.w += hb.w * wb;
  }
  if (j < je) {
    int2 pa = csr[j];
    float4 ha = e4[(size_t)z[pa.x] * 32 + q];
    float wa = __int_as_float(pa.y);
    s0.x += ha.x * wa; s0.y += ha.y * wa; s0.z += ha.z * wa; s0.w += ha.w * wa;
  }
  float4 s = {s0.x + s1.x, s0.y + s1.y, s0.z + s1.z, s0.w + s1.w};
  s.x += __shfl_xor(s.x, 32);
  s.y += __shfl_xor(s.y, 32);
  s.z += __shfl_xor(s.z, 32);
  s.w += __shfl_xor(s.w, 32);
  if (h == 0) ((float4*)t)[(size_t)n * 32 + q] = s;
}

// layers 1,2: rows from x (64 MB, LLC-resident)
__global__ void aggx_k(const float* __restrict__ x, const int* __restrict__ off,
                       const int2* __restrict__ csr, float* __restrict__ t) {
  int n = (blockIdx.x * 256 + threadIdx.x) >> 6;
  int lane = threadIdx.x & 63;
  int h = lane >> 5, q = lane & 31;
  int jb = off[n], je = off[n + 1];
  float4 s0 = {0, 0, 0, 0}, s1 = {0, 0, 0, 0};
  const float4* x4 = (const float4*)x;
  int j = jb + h;
  for (; j + 2 < je; j += 4) {
    int2 pa = csr[j], pb = csr[j + 2];
    float4 ha = x4[(size_t)pa.x * 32 + q];
    float4 hb = x4[(size_t)pb.x * 32 + q];
    float wa = __int_as_float(pa.y), wb = __int_as_float(pb.y);
    s0.x += ha.x * wa; s0.y += ha.y * wa; s0.z += ha.z * wa; s0.w += ha.w * wa;
    s1.x += hb.x * wb; s1.y += hb.y * wb; s1.z += hb.z * wb; s1.w += hb.w * wb;
  }
  if (j < je) {
    int2 pa = csr[j];
    float4 ha = x4[(size_t)pa.x * 32 + q];
    float wa = __int_as_float(pa.y);
    s0.x += ha.x * wa; s0.y += ha.y * wa; s0.z += ha.z * wa; s0.w += ha.w * wa;
  }
  float4 s = {s0.x + s1.x, s0.y + s1.y, s0.z + s1.z, s0.w + s1.w};
  s.x += __shfl_xor(s.x, 32);
  s.y += __shfl_xor(s.y, 32);
  s.z += __shfl_xor(s.z, 32);
  s.w += __shfl_xor(s.w, 32);
  if (h == 0) ((float4*)t)[(size_t)n * 32 + q] = s;
}

__device__ __forceinline__ void fma4(float4& acc, float s, const float4 w) {
  acc.x += s * w.x; acc.y += s * w.y; acc.z += s * w.z; acc.w += s * w.w;
}

// IN PLACE: buf[n][:] <- tanh( nd[n]*(buf[n][:] @ W) + b ); also emits per-row max.
__global__ void gemm_inplace_k(float* __restrict__ buf, const float* __restrict__ nd,
                               const float* __restrict__ W, const float* __restrict__ bias,
                               float* __restrict__ rowmax) {
  __shared__ float xt[64 * 128];   // 32 KB
  const int t = threadIdx.x;       // 256 threads
  const int rowBase = blockIdx.x * 64;
  float4* xt4 = (float4*)xt;
  const float4* g4 = (const float4*)(buf + (size_t)rowBase * 128);
  for (int i = t; i < 2048; i += 256) xt4[i] = g4[i];
  __syncthreads();
  const int w  = t >> 6;
  const int l  = t & 63;
  const int c4 = l & 31;
  const int rh = l >> 5;
  const int r0 = w * 16 + rh * 8;
  float4 acc[8];
#pragma unroll
  for (int r = 0; r < 8; ++r) acc[r] = {0, 0, 0, 0};
  const float4* W4 = (const float4*)W;
  for (int k4 = 0; k4 < 32; ++k4) {
    float4 xv[8];
#pragma unroll
    for (int r = 0; r < 8; ++r) xv[r] = xt4[(r0 + r) * 32 + k4];
    const float4 w0 = W4[(k4 * 4 + 0) * 32 + c4];
    const float4 w1 = W4[(k4 * 4 + 1) * 32 + c4];
    const float4 w2 = W4[(k4 * 4 + 2) * 32 + c4];
    const float4 w3 = W4[(k4 * 4 + 3) * 32 + c4];
#pragma unroll
    for (int r = 0; r < 8; ++r) {
      fma4(acc[r], xv[r].x, w0);
      fma4(acc[r], xv[r].y, w1);
      fma4(acc[r], xv[r].z, w2);
      fma4(acc[r], xv[r].w, w3);
    }
  }
  const float4 bb = ((const float4*)bias)[c4];
#pragma unroll
  for (int r = 0; r < 8; ++r) {
    const int row = rowBase + r0 + r;
    const float s = nd[row];
    float4 o;
    o.x = tanhf(acc[r].x * s + bb.x);
    o.y = tanhf(acc[r].y * s + bb.y);
    o.z = tanhf(acc[r].z * s + bb.z);
    o.w = tanhf(acc[r].w * s + bb.w);
    ((float4*)(buf + (size_t)row * 128))[c4] = o;
    float m = fmaxf(fmaxf(o.x, o.y), fmaxf(o.z, o.w));
    for (int d = 16; d; d >>= 1) m = fmaxf(m, __shfl_xor(m, d));
    if (c4 == 0) rowmax[row] = m;
  }
}

// layer 3, transform-first: y2[s] = dot(xs2[s], W3)  (ns already folded into csr w)
__global__ void gemv_y2_k(const float* __restrict__ x, const float* __restrict__ W3,
                          float* __restrict__ y2) {
  __shared__ float w[128];
  if (threadIdx.x < 128) w[threadIdx.x] = W3[threadIdx.x];
  __syncthreads();
  int lane = threadIdx.x & 63, wv = threadIdx.x >> 6;
  int n = blockIdx.x * 4 + wv;
  const float* xr = x + (size_t)n * 128;
  float p = xr[lane] * w[lane] + xr[lane + 64] * w[lane + 64];
  for (int o = 32; o; o >>= 1) p += __shfl_down(p, o);
  if (lane == 0) y2[n] = p;
}

// xs3[n] = tanh( nd_n * sum_j cw_j * y2[src_j] + b3 ); y2 is 512 KB (L2)
__global__ void agg3s_k(const float* __restrict__ y2, const int* __restrict__ off,
                        const int2* __restrict__ csr, const float* __restrict__ nd,
                        const float* __restrict__ b3, float* __restrict__ xs3) {
  int n = blockIdx.x * 256 + threadIdx.x;
  int jb = off[n], je = off[n + 1];
  float a0 = 0.f, a1 = 0.f;
  int j = jb;
  for (; j + 1 < je; j += 2) {
    int2 pa = csr[j], pb = csr[j + 1];
    a0 += __int_as_float(pa.y) * y2[pa.x];
    a1 += __int_as_float(pb.y) * y2[pb.x];
  }
  if (j < je) {
    int2 pa = csr[j];
    a0 += __int_as_float(pa.y) * y2[pa.x];
  }
  xs3[n] = tanhf((a0 + a1) * nd[n] + b3[0]);
}

// ======================= sort-pool =======================

__global__ void nodemax_small_k(const float* __restrict__ rm0, const float* __restrict__ rm1,
                                const float* __restrict__ rm2, const float* __restrict__ xs3,
                                float* __restrict__ nmax) {
  int n = blockIdx.x * 256 + threadIdx.x;
  nmax[n] = fmaxf(fmaxf(rm0[n], rm1[n]), fmaxf(rm2[n], xs3[n]));
}

// per-graph: sort 1024 (val,idx) pairs desc by val, asc by idx (jax.lax.top_k tie rule)
__global__ void topk_k(const float* __restrict__ nmax, int* __restrict__ sel) {
  __shared__ float v[1024];
  __shared__ int ix[1024];
  int g = blockIdx.x, t = threadIdx.x;  // 512 threads
  for (int i = t; i < 1024; i += 512) { v[i] = nmax[(size_t)g * 1024 + i]; ix[i] = i; }
  __syncthreads();
  for (int k = 2; k <= 1024; k <<= 1) {
    for (int j = k >> 1; j > 0; j >>= 1) {
      int i = ((t & ~(j - 1)) << 1) | (t & (j - 1));
      int pj = i | j;
      bool up = ((i & k) == 0);
      float va = v[i], vb = v[pj];
      int ia = ix[i], ib = ix[pj];
      bool b_bef_a = (vb > va) || (vb == va && ib < ia);
      bool a_bef_b = (va > vb) || (va == vb && ia < ib);
      bool sw = up ? b_bef_a : a_bef_b;
      if (sw) { v[i] = vb; v[pj] = va; ix[i] = ib; ix[pj] = ia; }
      __syncthreads();
    }
  }
  if (t < KTOP) sel[g * KTOP + t] = g * 1024 + ix[t];
}

// per selected node: ascending sort its 385 channel values (pad to 512 with +inf)
__global__ void sortpool_k(const int* __restrict__ sel, const float* __restrict__ xs0,
                           const float* __restrict__ xs1, const float* __restrict__ xs2,
                           const float* __restrict__ xs3, float* __restrict__ pooled) {
  __shared__ float sv[512];
  int blk = blockIdx.x, t = threadIdx.x;  // 256 threads
  int node = sel[blk];
  const float inf = __int_as_float(0x7f800000);
  for (int i = t; i < 512; i += 256) {
    float val;
    if (i < 128)      val = xs0[(size_t)node * 128 + i];
    else if (i < 256) val = xs1[(size_t)node * 128 + (i - 128)];
    else if (i < 384) val = xs2[(size_t)node * 128 + (i - 256)];
    else if (i == 384) val = xs3[node];
    else val = inf;
    sv[i] = val;
  }
  __syncthreads();
  for (int k = 2; k <= 512; k <<= 1) {
    for (int j = k >> 1; j > 0; j >>= 1) {
      int i = ((t & ~(j - 1)) << 1) | (t & (j - 1));
      int pj = i | j;
      bool up = ((i & k) == 0);
      float a = sv[i], b = sv[pj];
      if (up ? (a > b) : (a < b)) { sv[i] = b; sv[pj] = a; }
      __syncthreads();
    }
  }
  for (int i = t; i < DTOT; i += 256) pooled[(size_t)blk * DTOT + i] = sv[i];
}

// ======================= conv/MLP head (one block per graph) =======================

__global__ void head_k(const float* __restrict__ pooled,
                       const float* __restrict__ c1w, const float* __restrict__ c1b,
                       const float* __restrict__ c2w, const float* __restrict__ c2b,
                       const float* __restrict__ l1w, const float* __restrict__ l1b,
                       const float* __restrict__ l2w, const float* __restrict__ l2b,
                       float* __restrict__ out) {
  __shared__ float h1[16 * 60];
  __shared__ float h1p[16 * 30];
  __shared__ float h2f[832];
  __shared__ float h3[128];
  int g = blockIdx.x, t = threadIdx.x;  // 256 threads
  const float* pg = pooled + (size_t)g * KTOP * DTOT;
  for (int oi = t; oi < 960; oi += 256) {
    int c = oi & 15, kk = oi >> 4;
    const float* pr = pg + kk * DTOT;
    const float* wr = c1w + c * DTOT;
    float s = c1b[c];
    for (int d = 0; d < DTOT; ++d) s += pr[d] * wr[d];
    h1[c * 60 + kk] = fmaxf(s, 0.f);
  }
  __syncthreads();
  for (int i = t; i < 480; i += 256) {
    int c = i / 30, j = i % 30;
    h1p[c * 30 + j] = fmaxf(h1[c * 60 + 2 * j], h1[c * 60 + 2 * j + 1]);
  }
  __syncthreads();
  for (int i = t; i < 832; i += 256) {
    int oc = i / 26, x = i % 26;
    float s = c2b[oc];
    for (int ic = 0; ic < 16; ++ic)
#pragma unroll
      for (int w = 0; w < 5; ++w)
        s += h1p[ic * 30 + x + w] * c2w[oc * 80 + ic * 5 + w];
    h2f[i] = fmaxf(s, 0.f);
  }
  __syncthreads();
  if (t < 128) {
    float s = l1b[t];
    for (int d = 0; d < 832; ++d) s += h2f[d] * l1w[d * 128 + t];
    h3[t] = fmaxf(s, 0.f);
  }
  __syncthreads();
  if (t < 64) {
    float p = h3[t] * l2w[t] + h3[t + 64] * l2w[t + 64];
    for (int o = 32; o; o >>= 1) p += __shfl_down(p, o);
    if (t == 0) out[g] = p + l2b[0];
  }
}

// ======================= driver =======================

extern "C" void kernel_launch(void* const* d_in, const int* in_sizes, int n_in,
                              void* d_out, int out_size, void* d_ws, size_t ws_size,
                              hipStream_t stream) {
  const int* z = (const int*)d_in[0];
  const int* src = (const int*)d_in[1];
  const int* dst = (const int*)d_in[2];
  const float* ew = (const float*)d_in[3];
  const float* zemb = (const float*)d_in[4];
  const float* W0 = (const float*)d_in[5];  const float* b0 = (const float*)d_in[6];
  const float* W1 = (const float*)d_in[7];  const float* b1 = (const float*)d_in[8];
  const float* W2 = (const float*)d_in[9];  const float* b2 = (const float*)d_in[10];
  const float* W3 = (const float*)d_in[11]; const float* b3 = (const float*)d_in[12];
  const float* c1w = (const float*)d_in[13]; const float* c1b = (const float*)d_in[14];
  const float* c2w = (const float*)d_in[15]; const float* c2b = (const float*)d_in[16];
  const float* l1w = (const float*)d_in[17]; const float* l1b = (const float*)d_in[18];
  const float* l2w = (const float*)d_in[19]; const float* l2b = (const float*)d_in[20];
  float* out = (float*)d_out;

  // workspace layout (256B aligned); total ~236 MB
  char* ws = (char*)d_ws;
  size_t off = 0;
  auto alloc = [&](size_t bytes) {
    void* p = ws + off;
    off += (bytes + 255) & ~(size_t)255;
    return p;
  };
  int*   cnt     = (int*)alloc((size_t)2 * NN * 4);
  float* norm_s  = (float*)alloc((size_t)NN * 4);
  float* norm_d  = (float*)alloc((size_t)NN * 4);
  int*   csr_off = (int*)alloc((size_t)(NN + 1) * 4);
  int*   cursor  = (int*)alloc((size_t)NN * 4);
  int*   partials= (int*)alloc(1024);
  int2*  csr     = (int2*)alloc((size_t)NE * 8);
  float* xs0     = (float*)alloc((size_t)NN * 128 * 4);
  float* xs1     = (float*)alloc((size_t)NN * 128 * 4);
  float* xs2     = (float*)alloc((size_t)NN * 128 * 4);
  float* xs3     = (float*)alloc((size_t)NN * 4);
  float* y2      = (float*)alloc((size_t)NN * 4);
  float* rm0     = (float*)alloc((size_t)NN * 4);
  float* rm1     = (float*)alloc((size_t)NN * 4);
  float* rm2     = (float*)alloc((size_t)NN * 4);
  float* nmax    = (float*)alloc((size_t)NN * 4);
  int*   sel     = (int*)alloc((size_t)NG * KTOP * 4);
  float* pooled  = (float*)alloc((size_t)NG * KTOP * DTOT * 4);
  (void)in_sizes; (void)n_in; (void)out_size;
  if (ws_size < off) return;   // guard: never write OOB

  int* cnt_s = cnt;
  int* cnt_d = cnt + NN;

  // ---- CSR build + norms ----
  zero2_k<<<2 * NN / 256, 256, 0, stream>>>(cnt);
  count_k<<<NE / 256, 256, 0, stream>>>(src, dst, cnt_s, cnt_d);
  norm_k<<<NN / 256, 256, 0, stream>>>(cnt_s, cnt_d, norm_s, norm_d);
  scan1_k<<<128, 256, 0, stream>>>(cnt_d, csr_off, partials);
  scan2_k<<<1, 128, 0, stream>>>(partials);
  scan3_k<<<128, 256, 0, stream>>>(csr_off, partials, cursor);
  fill_k<<<NE / 256, 256, 0, stream>>>(src, dst, ew, norm_s, cursor, csr);

  // ---- 3 GraphConv layers 128->128 (aggregate-first, in-place transform) ----
  agg0_k<<<NN * 64 / 256, 256, 0, stream>>>(z, zemb, csr_off, csr, xs0);
  gemm_inplace_k<<<NN / 64, 256, 0, stream>>>(xs0, norm_d, W0, b0, rm0);
  aggx_k<<<NN * 64 / 256, 256, 0, stream>>>(xs0, csr_off, csr, xs1);
  gemm_inplace_k<<<NN / 64, 256, 0, stream>>>(xs1, norm_d, W1, b1, rm1);
  aggx_k<<<NN * 64 / 256, 256, 0, stream>>>(xs1, csr_off, csr, xs2);
  gemm_inplace_k<<<NN / 64, 256, 0, stream>>>(xs2, norm_d, W2, b2, rm2);

  // ---- layer 3: 128->1, transform-first (gather 4B scalars, not 512B rows) ----
  gemv_y2_k<<<NN / 4, 256, 0, stream>>>(xs2, W3, y2);
  agg3s_k<<<NN / 256, 256, 0, stream>>>(y2, csr_off, csr, norm_d, b3, xs3);

  // ---- sort-pool ----
  nodemax_small_k<<<NN / 256, 256, 0, stream>>>(rm0, rm1, rm2, xs3, nmax);
  topk_k<<<NG, 512, 0, stream>>>(nmax, sel);
  sortpool_k<<<NG * KTOP, 256, 0, stream>>>(sel, xs0, xs1, xs2, xs3, pooled);

  // ---- head ----
  head_k<<<NG, 256, 0, stream>>>(pooled, c1w, c1b, c2w, c2b, l1w, l1b, l2w, l2b, out);
}

// Round 13
// 1050.792 us; speedup vs baseline: 1.2853x; 1.1272x over previous
//
#include <hip/hip_runtime.h>

#define NN 131072        // nodes
#define NE 2097152       // edges
#define NG 128           // graphs
#define KTOP 60
#define DTOT 385
#define EPB 2048         // edges per partition block

// ======================= radix CSR build (no per-edge global atomics) =======================

__global__ void zero_small_k(int* __restrict__ p, int n) {
  int i = blockIdx.x * 256 + threadIdx.x;
  if (i < n) p[i] = 0;
}

// per-block LDS 128-bin histograms of dst>>10 and src>>10, merged globally
__global__ void bucketcnt_k(const int* __restrict__ src, const int* __restrict__ dst,
                            int* __restrict__ gd, int* __restrict__ gs) {
  __shared__ int hd[128], hs[128];
  int t = threadIdx.x;
  if (t < 128) { hd[t] = 0; hs[t] = 0; }
  __syncthreads();
  int base = blockIdx.x * EPB;
#pragma unroll
  for (int i = 0; i < EPB / 256; ++i) {
    int e = base + i * 256 + t;
    atomicAdd(&hd[dst[e] >> 10], 1);
    atomicAdd(&hs[src[e] >> 10], 1);
  }
  __syncthreads();
  if (t < 128) { atomicAdd(&gd[t], hd[t]); atomicAdd(&gs[t], hs[t]); }
}

// single block: exclusive scan of both 128-bin histograms; init cursors
__global__ void bucketscan_k(const int* __restrict__ gd, const int* __restrict__ gs,
                             int* __restrict__ offd, int* __restrict__ offs,
                             int* __restrict__ curd, int* __restrict__ curs,
                             int* __restrict__ csr_off) {
  __shared__ int a[128], b[128];
  int t = threadIdx.x;   // 128 threads
  int vd = gd[t], vs = gs[t];
  int xd = vd, xs = vs;
  a[t] = xd; b[t] = xs;
  __syncthreads();
  for (int o = 1; o < 128; o <<= 1) {
    int yd = (t >= o) ? a[t - o] : 0;
    int ys = (t >= o) ? b[t - o] : 0;
    __syncthreads();
    xd += yd; xs += ys; a[t] = xd; b[t] = xs;
    __syncthreads();
  }
  offd[t] = xd - vd; offs[t] = xs - vs;
  curd[t] = xd - vd; curs[t] = xs - vs;
  if (t == 0) { offd[128] = NE; offs[128] = NE; csr_off[NN] = NE; }
}

// partition edges by dst-bucket (packed {src | dst_local<<17, ew}) and src values by src-bucket
__global__ void part_k(const int* __restrict__ src, const int* __restrict__ dst,
                       const float* __restrict__ ew,
                       int* __restrict__ curd, int* __restrict__ curs,
                       uint2* __restrict__ ebuf, int* __restrict__ sbuf) {
  __shared__ int hd[128], hs[128], bd[128], bs[128];
  int t = threadIdx.x;
  if (t < 128) { hd[t] = 0; hs[t] = 0; }
  __syncthreads();
  int base = blockIdx.x * EPB;
  int s[8], d[8], rd[8], rs[8]; float w[8];
#pragma unroll
  for (int i = 0; i < 8; ++i) {
    int e = base + i * 256 + t;
    s[i] = src[e]; d[i] = dst[e]; w[i] = ew[e];
    rd[i] = atomicAdd(&hd[d[i] >> 10], 1);   // rank within (block, dst-bin)
    rs[i] = atomicAdd(&hs[s[i] >> 10], 1);   // rank within (block, src-bin)
  }
  __syncthreads();
  if (t < 128) {
    bd[t] = atomicAdd(&curd[t], hd[t]);      // reserve contiguous range per (block,bin)
    bs[t] = atomicAdd(&curs[t], hs[t]);
  }
  __syncthreads();
#pragma unroll
  for (int i = 0; i < 8; ++i) {
    int bind = d[i] >> 10;
    unsigned packed = (unsigned)s[i] | ((unsigned)(d[i] & 1023) << 17);
    ebuf[bd[bind] + rd[i]] = make_uint2(packed, __float_as_uint(w[i]));
    sbuf[bs[s[i] >> 10] + rs[i]] = s[i];
  }
}

// per src-bucket LDS histogram -> norm_s (out-degree)
__global__ void outdeg_k(const int* __restrict__ sbuf, const int* __restrict__ offs,
                         float* __restrict__ norm_s) {
  __shared__ int h[1024];
  int g = blockIdx.x, t = threadIdx.x;  // 256 threads
  for (int i = t; i < 1024; i += 256) h[i] = 0;
  __syncthreads();
  int jb = offs[g], je = offs[g + 1];
  for (int j = jb + t; j < je; j += 256) atomicAdd(&h[sbuf[j] & 1023], 1);
  __syncthreads();
  for (int i = t; i < 1024; i += 256) {
    int c = h[i]; c = c < 1 ? 1 : c;
    norm_s[g * 1024 + i] = 1.0f / sqrtf((float)c);
  }
}

// per dst-bucket: in-degree hist + LDS scan -> csr_off/norm_d; LDS-cursor scatter -> csr
__global__ void csrbuild_k(const uint2* __restrict__ ebuf, const int* __restrict__ offd,
                           const float* __restrict__ norm_s,
                           int* __restrict__ csr_off, float* __restrict__ norm_d,
                           int2* __restrict__ csr) {
  __shared__ int hist[1024];
  __shared__ int excl[1024];   // becomes the scatter cursor
  __shared__ int part[256];
  int g = blockIdx.x, t = threadIdx.x;  // 256 threads
  for (int i = t; i < 1024; i += 256) hist[i] = 0;
  __syncthreads();
  int jb = offd[g], je = offd[g + 1];
  for (int j = jb + t; j < je; j += 256) atomicAdd(&hist[ebuf[j].x >> 17], 1);
  __syncthreads();
  int h0 = hist[4 * t], h1 = hist[4 * t + 1], h2 = hist[4 * t + 2], h3 = hist[4 * t + 3];
  int sum = h0 + h1 + h2 + h3;
  int x = sum;
  part[t] = x;
  __syncthreads();
  for (int o = 1; o < 256; o <<= 1) {
    int y = (t >= o) ? part[t - o] : 0;
    __syncthreads();
    x += y; part[t] = x;
    __syncthreads();
  }
  int e0 = x - sum;
  excl[4 * t]     = e0;
  excl[4 * t + 1] = e0 + h0;
  excl[4 * t + 2] = e0 + h0 + h1;
  excl[4 * t + 3] = e0 + h0 + h1 + h2;
  int nb = g * 1024;
  csr_off[nb + 4 * t]     = jb + e0;
  csr_off[nb + 4 * t + 1] = jb + e0 + h0;
  csr_off[nb + 4 * t + 2] = jb + e0 + h0 + h1;
  csr_off[nb + 4 * t + 3] = jb + e0 + h0 + h1 + h2;
  int c;
  c = h0 < 1 ? 1 : h0; norm_d[nb + 4 * t]     = 1.0f / sqrtf((float)c);
  c = h1 < 1 ? 1 : h1; norm_d[nb + 4 * t + 1] = 1.0f / sqrtf((float)c);
  c = h2 < 1 ? 1 : h2; norm_d[nb + 4 * t + 2] = 1.0f / sqrtf((float)c);
  c = h3 < 1 ? 1 : h3; norm_d[nb + 4 * t + 3] = 1.0f / sqrtf((float)c);
  __syncthreads();
  for (int j = jb + t; j < je; j += 256) {
    uint2 e = ebuf[j];
    int srcn = e.x & 0x1FFFF;
    int dl = e.x >> 17;
    float w = __uint_as_float(e.y) * norm_s[srcn];
    int slot = atomicAdd(&excl[dl], 1);
    csr[jb + slot] = make_int2(srcn, __float_as_int(w));
  }
}

// ======================= node feature pipeline =======================
// GraphConv linearity: out = tanh( nd_n * (sum_j ew_j*ns_sj*x_sj) @ W + b )

// One WAVE per node; two 32-lane halves split the edge list by parity.
__global__ void agg0_k(const int* __restrict__ z, const float* __restrict__ zemb,
                       const int* __restrict__ off, const int2* __restrict__ csr,
                       float* __restrict__ t) {
  int n = (blockIdx.x * 256 + threadIdx.x) >> 6;
  int lane = threadIdx.x & 63;
  int h = lane >> 5, q = lane & 31;
  int jb = off[n], je = off[n + 1];
  float4 s0 = {0, 0, 0, 0}, s1 = {0, 0, 0, 0};
  const float4* e4 = (const float4*)zemb;
  int j = jb + h;
  for (; j + 2 < je; j += 4) {
    int2 pa = csr[j], pb = csr[j + 2];
    float4 ha = e4[(size_t)z[pa.x] * 32 + q];
    float4 hb = e4[(size_t)z[pb.x] * 32 + q];
    float wa = __int_as_float(pa.y), wb = __int_as_float(pb.y);
    s0.x += ha.x * wa; s0.y += ha.y * wa; s0.z += ha.z * wa; s0.w += ha.w * wa;
    s1.x += hb.x * wb; s1.y += hb.y * wb; s1.z += hb.z * wb; s1.w += hb.w * wb;
  }
  if (j < je) {
    int2 pa = csr[j];
    float4 ha = e4[(size_t)z[pa.x] * 32 + q];
    float wa = __int_as_float(pa.y);
    s0.x += ha.x * wa; s0.y += ha.y * wa; s0.z += ha.z * wa; s0.w += ha.w * wa;
  }
  float4 s = {s0.x + s1.x, s0.y + s1.y, s0.z + s1.z, s0.w + s1.w};
  s.x += __shfl_xor(s.x, 32);
  s.y += __shfl_xor(s.y, 32);
  s.z += __shfl_xor(s.z, 32);
  s.w += __shfl_xor(s.w, 32);
  if (h == 0) ((float4*)t)[(size_t)n * 32 + q] = s;
}

__global__ void aggx_k(const float* __restrict__ x, const int* __restrict__ off,
                       const int2* __restrict__ csr, float* __restrict__ t) {
  int n = (blockIdx.x * 256 + threadIdx.x) >> 6;
  int lane = threadIdx.x & 63;
  int h = lane >> 5, q = lane & 31;
  int jb = off[n], je = off[n + 1];
  float4 s0 = {0, 0, 0, 0}, s1 = {0, 0, 0, 0};
  const float4* x4 = (const float4*)x;
  int j = jb + h;
  for (; j + 2 < je; j += 4) {
    int2 pa = csr[j], pb = csr[j + 2];
    float4 ha = x4[(size_t)pa.x * 32 + q];
    float4 hb = x4[(size_t)pb.x * 32 + q];
    float wa = __int_as_float(pa.y), wb = __int_as_float(pb.y);
    s0.x += ha.x * wa; s0.y += ha.y * wa; s0.z += ha.z * wa; s0.w += ha.w * wa;
    s1.x += hb.x * wb; s1.y += hb.y * wb; s1.z += hb.z * wb; s1.w += hb.w * wb;
  }
  if (j < je) {
    int2 pa = csr[j];
    float4 ha = x4[(size_t)pa.x * 32 + q];
    float wa = __int_as_float(pa.y);
    s0.x += ha.x * wa; s0.y += ha.y * wa; s0.z += ha.z * wa; s0.w += ha.w * wa;
  }
  float4 s = {s0.x + s1.x, s0.y + s1.y, s0.z + s1.z, s0.w + s1.w};
  s.x += __shfl_xor(s.x, 32);
  s.y += __shfl_xor(s.y, 32);
  s.z += __shfl_xor(s.z, 32);
  s.w += __shfl_xor(s.w, 32);
  if (h == 0) ((float4*)t)[(size_t)n * 32 + q] = s;
}

__device__ __forceinline__ void fma4(float4& acc, float s, const float4 w) {
  acc.x += s * w.x; acc.y += s * w.y; acc.z += s * w.z; acc.w += s * w.w;
}

// IN PLACE: buf[n][:] <- tanh( nd[n]*(buf[n][:] @ W) + b ); also emits per-row max.
__global__ void gemm_inplace_k(float* __restrict__ buf, const float* __restrict__ nd,
                               const float* __restrict__ W, const float* __restrict__ bias,
                               float* __restrict__ rowmax) {
  __shared__ float xt[64 * 128];   // 32 KB
  const int t = threadIdx.x;       // 256 threads
  const int rowBase = blockIdx.x * 64;
  float4* xt4 = (float4*)xt;
  const float4* g4 = (const float4*)(buf + (size_t)rowBase * 128);
  for (int i = t; i < 2048; i += 256) xt4[i] = g4[i];
  __syncthreads();
  const int w  = t >> 6;
  const int l  = t & 63;
  const int c4 = l & 31;
  const int rh = l >> 5;
  const int r0 = w * 16 + rh * 8;
  float4 acc[8];
#pragma unroll
  for (int r = 0; r < 8; ++r) acc[r] = {0, 0, 0, 0};
  const float4* W4 = (const float4*)W;
  for (int k4 = 0; k4 < 32; ++k4) {
    float4 xv[8];
#pragma unroll
    for (int r = 0; r < 8; ++r) xv[r] = xt4[(r0 + r) * 32 + k4];
    const float4 w0 = W4[(k4 * 4 + 0) * 32 + c4];
    const float4 w1 = W4[(k4 * 4 + 1) * 32 + c4];
    const float4 w2 = W4[(k4 * 4 + 2) * 32 + c4];
    const float4 w3 = W4[(k4 * 4 + 3) * 32 + c4];
#pragma unroll
    for (int r = 0; r < 8; ++r) {
      fma4(acc[r], xv[r].x, w0);
      fma4(acc[r], xv[r].y, w1);
      fma4(acc[r], xv[r].z, w2);
      fma4(acc[r], xv[r].w, w3);
    }
  }
  const float4 bb = ((const float4*)bias)[c4];
#pragma unroll
  for (int r = 0; r < 8; ++r) {
    const int row = rowBase + r0 + r;
    const float s = nd[row];
    float4 o;
    o.x = tanhf(acc[r].x * s + bb.x);
    o.y = tanhf(acc[r].y * s + bb.y);
    o.z = tanhf(acc[r].z * s + bb.z);
    o.w = tanhf(acc[r].w * s + bb.w);
    ((float4*)(buf + (size_t)row * 128))[c4] = o;
    float m = fmaxf(fmaxf(o.x, o.y), fmaxf(o.z, o.w));
    for (int d = 16; d; d >>= 1) m = fmaxf(m, __shfl_xor(m, d));
    if (c4 == 0) rowmax[row] = m;
  }
}

// layer 3, transform-first: y2[s] = dot(xs2[s], W3)
__global__ void gemv_y2_k(const float* __restrict__ x, const float* __restrict__ W3,
                          float* __restrict__ y2) {
  __shared__ float w[128];
  if (threadIdx.x < 128) w[threadIdx.x] = W3[threadIdx.x];
  __syncthreads();
  int lane = threadIdx.x & 63, wv = threadIdx.x >> 6;
  int n = blockIdx.x * 4 + wv;
  const float* xr = x + (size_t)n * 128;
  float p = xr[lane] * w[lane] + xr[lane + 64] * w[lane + 64];
  for (int o = 32; o; o >>= 1) p += __shfl_down(p, o);
  if (lane == 0) y2[n] = p;
}

// xs3[n] = tanh( nd_n * sum_j cw_j * y2[src_j] + b3 )
__global__ void agg3s_k(const float* __restrict__ y2, const int* __restrict__ off,
                        const int2* __restrict__ csr, const float* __restrict__ nd,
                        const float* __restrict__ b3, float* __restrict__ xs3) {
  int n = blockIdx.x * 256 + threadIdx.x;
  int jb = off[n], je = off[n + 1];
  float a0 = 0.f, a1 = 0.f;
  int j = jb;
  for (; j + 1 < je; j += 2) {
    int2 pa = csr[j], pb = csr[j + 1];
    a0 += __int_as_float(pa.y) * y2[pa.x];
    a1 += __int_as_float(pb.y) * y2[pb.x];
  }
  if (j < je) {
    int2 pa = csr[j];
    a0 += __int_as_float(pa.y) * y2[pa.x];
  }
  xs3[n] = tanhf((a0 + a1) * nd[n] + b3[0]);
}

// ======================= sort-pool =======================

__global__ void nodemax_small_k(const float* __restrict__ rm0, const float* __restrict__ rm1,
                                const float* __restrict__ rm2, const float* __restrict__ xs3,
                                float* __restrict__ nmax) {
  int n = blockIdx.x * 256 + threadIdx.x;
  nmax[n] = fmaxf(fmaxf(rm0[n], rm1[n]), fmaxf(rm2[n], xs3[n]));
}

// per-graph: sort 1024 (val,idx) pairs desc by val, asc by idx (jax.lax.top_k tie rule)
__global__ void topk_k(const float* __restrict__ nmax, int* __restrict__ sel) {
  __shared__ float v[1024];
  __shared__ int ix[1024];
  int g = blockIdx.x, t = threadIdx.x;  // 512 threads
  for (int i = t; i < 1024; i += 512) { v[i] = nmax[(size_t)g * 1024 + i]; ix[i] = i; }
  __syncthreads();
  for (int k = 2; k <= 1024; k <<= 1) {
    for (int j = k >> 1; j > 0; j >>= 1) {
      int i = ((t & ~(j - 1)) << 1) | (t & (j - 1));
      int pj = i | j;
      bool up = ((i & k) == 0);
      float va = v[i], vb = v[pj];
      int ia = ix[i], ib = ix[pj];
      bool b_bef_a = (vb > va) || (vb == va && ib < ia);
      bool a_bef_b = (va > vb) || (va == vb && ia < ib);
      bool sw = up ? b_bef_a : a_bef_b;
      if (sw) { v[i] = vb; v[pj] = va; ix[i] = ib; ix[pj] = ia; }
      __syncthreads();
    }
  }
  if (t < KTOP) sel[g * KTOP + t] = g * 1024 + ix[t];
}

// per selected node: ascending sort its 385 channel values (pad to 512 with +inf)
__global__ void sortpool_k(const int* __restrict__ sel, const float* __restrict__ xs0,
                           const float* __restrict__ xs1, const float* __restrict__ xs2,
                           const float* __restrict__ xs3, float* __restrict__ pooled) {
  __shared__ float sv[512];
  int blk = blockIdx.x, t = threadIdx.x;  // 256 threads
  int node = sel[blk];
  const float inf = __int_as_float(0x7f800000);
  for (int i = t; i < 512; i += 256) {
    float val;
    if (i < 128)      val = xs0[(size_t)node * 128 + i];
    else if (i < 256) val = xs1[(size_t)node * 128 + (i - 128)];
    else if (i < 384) val = xs2[(size_t)node * 128 + (i - 256)];
    else if (i == 384) val = xs3[node];
    else val = inf;
    sv[i] = val;
  }
  __syncthreads();
  for (int k = 2; k <= 512; k <<= 1) {
    for (int j = k >> 1; j > 0; j >>= 1) {
      int i = ((t & ~(j - 1)) << 1) | (t & (j - 1));
      int pj = i | j;
      bool up = ((i & k) == 0);
      float a = sv[i], b = sv[pj];
      if (up ? (a > b) : (a < b)) { sv[i] = b; sv[pj] = a; }
      __syncthreads();
    }
  }
  for (int i = t; i < DTOT; i += 256) pooled[(size_t)blk * DTOT + i] = sv[i];
}

// ======================= conv/MLP head (one block per graph) =======================

__global__ void head_k(const float* __restrict__ pooled,
                       const float* __restrict__ c1w, const float* __restrict__ c1b,
                       const float* __restrict__ c2w, const float* __restrict__ c2b,
                       const float* __restrict__ l1w, const float* __restrict__ l1b,
                       const float* __restrict__ l2w, const float* __restrict__ l2b,
                       float* __restrict__ out) {
  __shared__ float h1[16 * 60];
  __shared__ float h1p[16 * 30];
  __shared__ float h2f[832];
  __shared__ float h3[128];
  int g = blockIdx.x, t = threadIdx.x;  // 256 threads
  const float* pg = pooled + (size_t)g * KTOP * DTOT;
  for (int oi = t; oi < 960; oi += 256) {
    int c = oi & 15, kk = oi >> 4;
    const float* pr = pg + kk * DTOT;
    const float* wr = c1w + c * DTOT;
    float s = c1b[c];
    for (int d = 0; d < DTOT; ++d) s += pr[d] * wr[d];
    h1[c * 60 + kk] = fmaxf(s, 0.f);
  }
  __syncthreads();
  for (int i = t; i < 480; i += 256) {
    int c = i / 30, j = i % 30;
    h1p[c * 30 + j] = fmaxf(h1[c * 60 + 2 * j], h1[c * 60 + 2 * j + 1]);
  }
  __syncthreads();
  for (int i = t; i < 832; i += 256) {
    int oc = i / 26, x = i % 26;
    float s = c2b[oc];
    for (int ic = 0; ic < 16; ++ic)
#pragma unroll
      for (int w = 0; w < 5; ++w)
        s += h1p[ic * 30 + x + w] * c2w[oc * 80 + ic * 5 + w];
    h2f[i] = fmaxf(s, 0.f);
  }
  __syncthreads();
  if (t < 128) {
    float s = l1b[t];
    for (int d = 0; d < 832; ++d) s += h2f[d] * l1w[d * 128 + t];
    h3[t] = fmaxf(s, 0.f);
  }
  __syncthreads();
  if (t < 64) {
    float p = h3[t] * l2w[t] + h3[t + 64] * l2w[t + 64];
    for (int o = 32; o; o >>= 1) p += __shfl_down(p, o);
    if (t == 0) out[g] = p + l2b[0];
  }
}

// ======================= driver =======================

extern "C" void kernel_launch(void* const* d_in, const int* in_sizes, int n_in,
                              void* d_out, int out_size, void* d_ws, size_t ws_size,
                              hipStream_t stream) {
  const int* z = (const int*)d_in[0];
  const int* src = (const int*)d_in[1];
  const int* dst = (const int*)d_in[2];
  const float* ew = (const float*)d_in[3];
  const float* zemb = (const float*)d_in[4];
  const float* W0 = (const float*)d_in[5];  const float* b0 = (const float*)d_in[6];
  const float* W1 = (const float*)d_in[7];  const float* b1 = (const float*)d_in[8];
  const float* W2 = (const float*)d_in[9];  const float* b2 = (const float*)d_in[10];
  const float* W3 = (const float*)d_in[11]; const float* b3 = (const float*)d_in[12];
  const float* c1w = (const float*)d_in[13]; const float* c1b = (const float*)d_in[14];
  const float* c2w = (const float*)d_in[15]; const float* c2b = (const float*)d_in[16];
  const float* l1w = (const float*)d_in[17]; const float* l1b = (const float*)d_in[18];
  const float* l2w = (const float*)d_in[19]; const float* l2b = (const float*)d_in[20];
  float* out = (float*)d_out;

  // workspace layout (256B aligned); total ~235 MB
  char* ws = (char*)d_ws;
  size_t off = 0;
  auto alloc = [&](size_t bytes) {
    void* p = ws + off;
    off += (bytes + 255) & ~(size_t)255;
    return p;
  };
  int*   gcnt    = (int*)alloc(256 * 4);        // gd | gs
  int*   offd    = (int*)alloc(129 * 4);
  int*   offs    = (int*)alloc(129 * 4);
  int*   curd    = (int*)alloc(128 * 4);
  int*   curs    = (int*)alloc(128 * 4);
  int*   csr_off = (int*)alloc((size_t)(NN + 1) * 4);
  float* norm_s  = (float*)alloc((size_t)NN * 4);
  float* norm_d  = (float*)alloc((size_t)NN * 4);
  int2*  csr     = (int2*)alloc((size_t)NE * 8);
  float* xs0     = (float*)alloc((size_t)NN * 128 * 4);
  float* xs1     = (float*)alloc((size_t)NN * 128 * 4);
  float* xs2     = (float*)alloc((size_t)NN * 128 * 4);
  float* xs3     = (float*)alloc((size_t)NN * 4);
  float* y2      = (float*)alloc((size_t)NN * 4);
  float* rm0     = (float*)alloc((size_t)NN * 4);
  float* rm1     = (float*)alloc((size_t)NN * 4);
  float* rm2     = (float*)alloc((size_t)NN * 4);
  float* nmax    = (float*)alloc((size_t)NN * 4);
  int*   sel     = (int*)alloc((size_t)NG * KTOP * 4);
  float* pooled  = (float*)alloc((size_t)NG * KTOP * DTOT * 4);
  (void)in_sizes; (void)n_in; (void)out_size;
  if (ws_size < off) return;   // guard: never write OOB

  int* gd = gcnt;
  int* gs = gcnt + 128;
  // ebuf (16.8 MB) + sbuf (8.4 MB) alias xs0 (dead until agg0_k)
  uint2* ebuf = (uint2*)xs0;
  int*   sbuf = (int*)(xs0 + (size_t)NE * 2);

  // ---- radix CSR build ----
  zero_small_k<<<1, 256, 0, stream>>>(gcnt, 256);
  bucketcnt_k<<<NE / EPB, 256, 0, stream>>>(src, dst, gd, gs);
  bucketscan_k<<<1, 128, 0, stream>>>(gd, gs, offd, offs, curd, curs, csr_off);
  part_k<<<NE / EPB, 256, 0, stream>>>(src, dst, ew, curd, curs, ebuf, sbuf);
  outdeg_k<<<NG, 256, 0, stream>>>(sbuf, offs, norm_s);
  csrbuild_k<<<NG, 256, 0, stream>>>(ebuf, offd, norm_s, csr_off, norm_d, csr);

  // ---- 3 GraphConv layers 128->128 (aggregate-first, in-place transform) ----
  agg0_k<<<NN * 64 / 256, 256, 0, stream>>>(z, zemb, csr_off, csr, xs0);
  gemm_inplace_k<<<NN / 64, 256, 0, stream>>>(xs0, norm_d, W0, b0, rm0);
  aggx_k<<<NN * 64 / 256, 256, 0, stream>>>(xs0, csr_off, csr, xs1);
  gemm_inplace_k<<<NN / 64, 256, 0, stream>>>(xs1, norm_d, W1, b1, rm1);
  aggx_k<<<NN * 64 / 256, 256, 0, stream>>>(xs1, csr_off, csr, xs2);
  gemm_inplace_k<<<NN / 64, 256, 0, stream>>>(xs2, norm_d, W2, b2, rm2);

  // ---- layer 3: 128->1, transform-first ----
  gemv_y2_k<<<NN / 4, 256, 0, stream>>>(xs2, W3, y2);
  agg3s_k<<<NN / 256, 256, 0, stream>>>(y2, csr_off, csr, norm_d, b3, xs3);

  // ---- sort-pool ----
  nodemax_small_k<<<NN / 256, 256, 0, stream>>>(rm0, rm1, rm2, xs3, nmax);
  topk_k<<<NG, 512, 0, stream>>>(nmax, sel);
  sortpool_k<<<NG * KTOP, 256, 0, stream>>>(sel, xs0, xs1, xs2, xs3, pooled);

  // ---- head ----
  head_k<<<NG, 256, 0, stream>>>(pooled, c1w, c1b, c2w, c2b, l1w, l1b, l2w, l2b, out);
}